// Round 12
// baseline (9447.630 us; speedup 1.0000x reference)
//
#include <hip/hip_runtime.h>
#include <hip/hip_cooperative_groups.h>
#include <cmath>

namespace cg = cooperative_groups;

#define HH 48
#define WW 48
#define HWSZ 2304
#define BB 8
#define TT 32
#define PADPX 2688   // 64 guard + 2464 main + 160 guard
#define POFF 64
#define NWAVE 77     // waves of 32 px covering 2464 padded-linear px

typedef unsigned short u16;
typedef __attribute__((ext_vector_type(8))) short bf16x8;
typedef __attribute__((ext_vector_type(4))) float f32x4;

__device__ __forceinline__ u16 f2bf(float f) {
    unsigned int u = __float_as_uint(f);
    u = (u + 0x7fffu + ((u >> 16) & 1u)) >> 16;
    return (u16)u;
}
__device__ __forceinline__ float bf2f(u16 s) {
    return __uint_as_float(((unsigned int)s) << 16);
}
__device__ __forceinline__ float sigm(float x) { return 1.f / (1.f + __expf(-x)); }

// ---------------- weight fragments ----------------
// A frag = 16 hid x 32 k, 1KB; lane: m = lane&15, k = (lane>>4)*8 + j.
// wf frag index space:
//   [0,576)    : L0-h [hidg4][cs2][tap9][g4][pl2]   (w0 ic = cs*32 + k + 1)
//   [576,1008) : L1   [hidg2][cs3][tap9][g4][pl2]   (w1 ic = cs*32 + k)
// wxf (fp32):  [tap9][g4][mblock16][4]  -> w0 ic = 0 (the x channel), m=oc row
__global__ void wprep(const float* __restrict__ w0, const float* __restrict__ w1,
                      u16* __restrict__ wf, float* __restrict__ wxf)
{
    const int gid = blockIdx.x * 256 + threadIdx.x;
    if (gid < 1008 * 64) {
        const int lane = gid & 63;
        const int f = gid >> 6;
        const int m = lane & 15;
        const int kh = lane >> 4;
        float v[8];
        int pl;
        if (f < 576) {
            pl = f & 1;
            const int g = (f >> 1) & 3;
            int r = f >> 3;
            const int tap = r % 9; r /= 9;
            const int cs = r & 1;
            const int hidg = r >> 1;
            const int oc = g * 64 + hidg * 16 + m;
            #pragma unroll
            for (int j = 0; j < 8; ++j) {
                const int ic = cs * 32 + kh * 8 + j + 1;
                v[j] = w0[((size_t)oc * 65 + ic) * 9 + tap];
            }
        } else {
            const int f2 = f - 576;
            pl = f2 & 1;
            const int g = (f2 >> 1) & 3;
            int r = f2 >> 3;
            const int tap = r % 9; r /= 9;
            const int cs = r % 3;
            const int hidg = r / 3;
            const int oc = g * 32 + hidg * 16 + m;
            #pragma unroll
            for (int j = 0; j < 8; ++j) {
                const int ic = cs * 32 + kh * 8 + j;
                v[j] = w1[((size_t)oc * 96 + ic) * 9 + tap];
            }
        }
        u16 o[8] __attribute__((aligned(16)));
        #pragma unroll
        for (int j = 0; j < 8; ++j) {
            const u16 hi = f2bf(v[j]);
            o[j] = pl ? (u16)f2bf(v[j] - bf2f(hi)) : hi;
        }
        *(uint4*)(wf + (size_t)gid * 8) = *(const uint4*)o;
    }
    const int wx = gid - 1008 * 64;
    if (wx >= 0 && wx < 2304) {
        const int e = wx & 3;
        const int f4 = wx >> 2;
        const int mb = f4 & 15;
        const int tg = f4 >> 4;
        const int g = tg & 3;
        const int tap = tg >> 2;
        const int m = mb * 4 + e;
        wxf[wx] = w0[((size_t)(g * 64 + m) * 65 + 0) * 9 + tap];
    }
}

// x padded fp32 plane: [t][b][PADPX], zero guard (buffer memset beforehand).
__global__ void xprep(const float* __restrict__ x, float* __restrict__ xpad)
{
    const int gid = blockIdx.x * 256 + threadIdx.x;
    if (gid >= TT * BB * HWSZ) return;
    const int pix = gid % HWSZ;
    const int b = (gid / HWSZ) % BB;
    const int t = gid / (HWSZ * BB);
    const float v = x[((size_t)b * TT + t) * HWSZ + pix];
    const int y = pix / 48, xx = pix - y * 48;
    const int p = (y + 1) * 50 + (xx + 1);
    xpad[(size_t)(t * BB + b) * PADPX + POFF + p] = v;
}

// Persistent cooperative kernel: 240 blocks (always <= 256 CUs, so the
// cooperative-capacity check cannot fail), 512 threads. Each block does the
// work of two round-10 blocks: same (b, unit), frag chunks f and f+40.
// c-state lives in registers for the whole sequence. grid.sync() per step.
// h buffers: [kslot6][b][PADPX][16ch] hi/lo (kslot 0-3 = h0, 4-5 = h1).
__global__ __launch_bounds__(512, 4) void persist(
    u16* __restrict__ bufA_hi, u16* __restrict__ bufA_lo,
    u16* __restrict__ bufB_hi, u16* __restrict__ bufB_lo,
    const float* __restrict__ xpad,
    const u16* __restrict__ wf, const float* __restrict__ wxf,
    const float* __restrict__ b0, const float* __restrict__ b1,
    float* __restrict__ seq,
    const float* __restrict__ wl, const float* __restrict__ blp,
    float* __restrict__ out)
{
    cg::grid_group gg = cg::this_grid();

    const int tid = threadIdx.x;
    const int lane = tid & 63;
    const int wv = tid >> 6;
    const int lid = blockIdx.x;          // 0..239
    const int b = lid & 7;               // 240 % 8 == 0: same b for both halves
    const int r0 = lid >> 3;             // 0..29
    const int unit = r0 % 6;             // same unit for r0 and r0+30
    const int pg = r0 / 6;               // 0..4
    const bool isL0 = unit < 4;
    const int frag0 = pg * 8 + wv;       // 0..39, always < NWAVE
    const int frag1 = frag0 + 40;        // 40..79, active if < NWAVE
    const int hidg = isL0 ? unit : (unit - 4);

    const int n   = lane & 15;        // px col within tile; also A row m
    const int khb = (lane >> 4) & 1;  // within-slot 8-ch half for B
    const int ksl = lane >> 5;        // slot parity for B
    const int mq  = lane >> 4;        // D row quarter: m = mq*4 + e

    // bias fragments, hoisted once (D: col=lane&15, row m=mq*4+e)
    const float* bias = isL0 ? b0 : b1;
    const int CHID = isL0 ? 64 : 32;
    f32x4 bias_v[4];
    #pragma unroll
    for (int g = 0; g < 4; ++g)
        bias_v[g] = *(const f32x4*)(bias + g * CHID + hidg * 16 + mq * 4);

    // persistent c-state: 2 chunks x 2 px-tiles per lane (statically named)
    f32x4 cvA0 = {0.f, 0.f, 0.f, 0.f};
    f32x4 cvA1 = {0.f, 0.f, 0.f, 0.f};
    f32x4 cvB0 = {0.f, 0.f, 0.f, 0.f};
    f32x4 cvB1 = {0.f, 0.f, 0.f, 0.f};

    for (int s = 0; s <= TT; ++s) {
        const u16* in_hi = (s & 1) ? bufB_hi : bufA_hi;
        const u16* in_lo = (s & 1) ? bufB_lo : bufA_lo;
        u16* out_hi = (s & 1) ? bufA_hi : bufB_hi;
        u16* out_lo = (s & 1) ? bufA_lo : bufB_lo;
        const bool work = isL0 ? (s < TT) : (s >= 1);

        auto chunk = [&](int p0, f32x4& cv0r, f32x4& cv1r) {
            f32x4 acc[2][4];
            #pragma unroll
            for (int g = 0; g < 4; ++g) {
                acc[0][g] = bias_v[g];
                acc[1][g] = bias_v[g];
            }

            auto conv32 = [&](int slotpair, const u16* af) {
                const size_t base = ((size_t)((slotpair * 2 + ksl) * 8 + b) * PADPX
                                     + POFF + p0 + n) * 16 + khb * 8;
                const u16* pbh = in_hi + base;
                const u16* pbl = in_lo + base;
                const char* pa = (const char*)af + lane * 16;
                #pragma unroll
                for (int tap = 0; tap < 9; ++tap) {
                    const int toff = ((tap / 3) - 1) * 50 + (tap % 3) - 1;
                    const bf16x8 Bh0 = *(const bf16x8*)(pbh + (long)toff * 16);
                    const bf16x8 Bl0 = *(const bf16x8*)(pbl + (long)toff * 16);
                    const bf16x8 Bh1 = *(const bf16x8*)(pbh + (long)(toff + 16) * 16);
                    const bf16x8 Bl1 = *(const bf16x8*)(pbl + (long)(toff + 16) * 16);
                    #pragma unroll
                    for (int g = 0; g < 4; ++g) {
                        const bf16x8 Ah = *(const bf16x8*)(pa + (size_t)(tap * 8 + g * 2 + 0) * 1024);
                        const bf16x8 Al = *(const bf16x8*)(pa + (size_t)(tap * 8 + g * 2 + 1) * 1024);
                        acc[0][g] = __builtin_amdgcn_mfma_f32_16x16x32_bf16(Al, Bh0, acc[0][g], 0, 0, 0);
                        acc[1][g] = __builtin_amdgcn_mfma_f32_16x16x32_bf16(Al, Bh1, acc[1][g], 0, 0, 0);
                        acc[0][g] = __builtin_amdgcn_mfma_f32_16x16x32_bf16(Ah, Bl0, acc[0][g], 0, 0, 0);
                        acc[1][g] = __builtin_amdgcn_mfma_f32_16x16x32_bf16(Ah, Bl1, acc[1][g], 0, 0, 0);
                        acc[0][g] = __builtin_amdgcn_mfma_f32_16x16x32_bf16(Ah, Bh0, acc[0][g], 0, 0, 0);
                        acc[1][g] = __builtin_amdgcn_mfma_f32_16x16x32_bf16(Ah, Bh1, acc[1][g], 0, 0, 0);
                    }
                }
            };

            if (isL0) {
                const int t = s;
                conv32(0, wf + (size_t)((hidg * 2 + 0) * 72) * 512);
                conv32(1, wf + (size_t)((hidg * 2 + 1) * 72) * 512);
                // ---- x channel on VALU, exact fp32 ----
                const float* xrow = xpad + (size_t)(t * BB + b) * PADPX + POFF + p0 + n;
                #pragma unroll
                for (int tap = 0; tap < 9; ++tap) {
                    const int toff = ((tap / 3) - 1) * 50 + (tap % 3) - 1;
                    const float xv0 = xrow[toff];
                    const float xv1 = xrow[toff + 16];
                    #pragma unroll
                    for (int g = 0; g < 4; ++g) {
                        const f32x4 wvx = *(const f32x4*)(wxf +
                            ((size_t)(tap * 4 + g) * 16 + hidg * 4 + mq) * 4);
                        #pragma unroll
                        for (int e = 0; e < 4; ++e) {
                            acc[0][g][e] += wvx[e] * xv0;
                            acc[1][g][e] += wvx[e] * xv1;
                        }
                    }
                }
            } else {
                conv32(0, wf + (size_t)(576 + (hidg * 3 + 0) * 72) * 512);
                conv32(1, wf + (size_t)(576 + (hidg * 3 + 1) * 72) * 512);
                conv32(2, wf + (size_t)(576 + (hidg * 3 + 2) * 72) * 512);
            }

            // ---- epilogue: LSTM pointwise; lane owns 2 px, 4 m-rows ----
            float* seq_t = seq + (size_t)(s - 1) * 32 * HWSZ;
            #pragma unroll
            for (int tl = 0; tl < 2; ++tl) {
                f32x4& cvr = tl ? cv1r : cv0r;
                const int p = p0 + tl * 16 + n;
                const int py = p / 50, pxx = p - py * 50;
                const bool valid = (py >= 1) && (py <= 48) && (pxx >= 1) && (pxx <= 48);
                const int pix = (py - 1) * 48 + (pxx - 1);
                const bool doseq = (!isL0) && (b == 0) && valid;
                f32x4 cn;
                short4 sh, sl;
                #pragma unroll
                for (int e = 0; e < 4; ++e) {
                    const float i_ = sigm(acc[tl][0][e]);
                    const float f_ = sigm(acc[tl][1][e]);
                    const float o_ = sigm(acc[tl][2][e]);
                    const float g_ = tanhf(acc[tl][3][e]);
                    const float cvv = f_ * cvr[e] + i_ * g_;
                    const float hv = o_ * tanhf(cvv);
                    cn[e] = cvv;
                    const u16 hi = f2bf(hv);
                    ((u16*)&sh)[e] = (short)hi;
                    ((u16*)&sl)[e] = (short)f2bf(hv - bf2f(hi));
                    if (doseq) {
                        const int ch = hidg * 16 + mq * 4 + e;
                        seq_t[(size_t)ch * HWSZ + pix] = hv;
                    }
                }
                cvr = cn;
                if (valid) {
                    const int kslot = (isL0 ? 0 : 4) + hidg;
                    const size_t ob = (((size_t)kslot * 8 + b) * PADPX + POFF + p) * 16 + mq * 4;
                    *(short4*)(out_hi + ob) = sh;
                    *(short4*)(out_lo + ob) = sl;
                }
            }
        };

        if (work) {
            chunk(frag0 * 32, cvA0, cvA1);
            if (frag1 < NWAVE) chunk(frag1 * 32, cvB0, cvB1);
        }
        gg.sync();
    }

    // ---- head: out[k] = bl + sum_j wl[j] * seq_flat[32k+j] ----
    const int stride = gridDim.x * blockDim.x;
    const float blv = blp[0];
    float wls[32];
    #pragma unroll
    for (int q = 0; q < 32; ++q) wls[q] = wl[q];
    for (int k = blockIdx.x * blockDim.x + threadIdx.x; k < TT * HWSZ; k += stride) {
        const float4* p = (const float4*)(seq + (size_t)k * 32);
        float ssum = blv;
        #pragma unroll
        for (int q = 0; q < 8; ++q) {
            float4 f = p[q];
            ssum += f.x * wls[q * 4 + 0] + f.y * wls[q * 4 + 1]
                  + f.z * wls[q * 4 + 2] + f.w * wls[q * 4 + 3];
        }
        out[k] = ssum;
    }
}

extern "C" void kernel_launch(void* const* d_in, const int* in_sizes, int n_in,
                              void* d_out, int out_size, void* d_ws, size_t ws_size,
                              hipStream_t stream)
{
    const float* x  = (const float*)d_in[0];   // [8,32,1,48,48]
    const float* w0 = (const float*)d_in[1];   // [256,65,3,3]
    const float* b0 = (const float*)d_in[2];   // [256]
    const float* w1 = (const float*)d_in[3];   // [128,96,3,3]
    const float* b1 = (const float*)d_in[4];   // [128]
    const float* wl = (const float*)d_in[5];   // [1,32]
    const float* bl = (const float*)d_in[6];   // [1]
    float* out = (float*)d_out;                // [73728]

    char* p = (char*)d_ws;
    auto alloc = [&](size_t bytes) -> char* {
        char* r = p; p += (bytes + 255) & ~(size_t)255; return r;
    };
    const size_t inbytes = (size_t)6 * BB * PADPX * 16 * 2;   // 3.94 MB
    u16* inA_hi = (u16*)alloc(inbytes);
    u16* inA_lo = (u16*)alloc(inbytes);
    u16* inB_hi = (u16*)alloc(inbytes);
    u16* inB_lo = (u16*)alloc(inbytes);
    const size_t xbytes = (size_t)TT * BB * PADPX * 4;        // 2.75 MB
    float* xpad = (float*)alloc(xbytes);
    u16* wfall  = (u16*)alloc((size_t)1008 * 1024);           // 1.03 MB
    float* wxf  = (float*)alloc((size_t)2304 * 4);
    float* seq  = (float*)alloc((size_t)TT * 32 * HWSZ * 4);  // 9.44 MB

    hipMemsetAsync(inA_hi, 0, inbytes, stream);
    hipMemsetAsync(inA_lo, 0, inbytes, stream);
    hipMemsetAsync(inB_hi, 0, inbytes, stream);
    hipMemsetAsync(inB_lo, 0, inbytes, stream);
    hipMemsetAsync(xpad, 0, xbytes, stream);

    wprep<<<(1008 * 64 + 2304 + 255) / 256, 256, 0, stream>>>(w0, w1, wfall, wxf);
    xprep<<<(TT * BB * HWSZ + 255) / 256, 256, 0, stream>>>(x, xpad);

    void* args[] = {
        (void*)&inA_hi, (void*)&inA_lo, (void*)&inB_hi, (void*)&inB_lo,
        (void*)&xpad, (void*)&wfall, (void*)&wxf,
        (void*)&b0, (void*)&b1, (void*)&seq,
        (void*)&wl, (void*)&bl, (void*)&out
    };
    hipLaunchCooperativeKernel((void*)persist, dim3(240), dim3(512),
                               args, 0, stream);
}

// Round 14
// 1547.559 us; speedup vs baseline: 6.1049x; 6.1049x over previous
//
#include <hip/hip_runtime.h>
#include <cmath>

#define HH 48
#define WW 48
#define HWSZ 2304
#define BB 8
#define TT 32
#define PADPX 2688   // 64 guard + 2464 main + 160 guard
#define POFF 64
#define NWAVE 77     // waves of 32 px covering 2464 padded-linear px

typedef unsigned short u16;
typedef __attribute__((ext_vector_type(8))) short bf16x8;
typedef __attribute__((ext_vector_type(4))) float f32x4;
typedef __attribute__((ext_vector_type(4))) short s16x4;

__device__ __forceinline__ u16 f2bf(float f) {
    unsigned int u = __float_as_uint(f);
    u = (u + 0x7fffu + ((u >> 16) & 1u)) >> 16;
    return (u16)u;
}
__device__ __forceinline__ float bf2f(u16 s) {
    return __uint_as_float(((unsigned int)s) << 16);
}
__device__ __forceinline__ float sigm(float x) { return 1.f / (1.f + __expf(-x)); }

// ---------------- weight fragments ----------------
// A frag = 16 hid x 32 k, 1KB; lane: m = lane&15, k = (lane>>4)*8 + j.
// wf frag index space:
//   [0,576)    : L0-h [hidg4][cs2][tap9][g4][pl2]   (w0 ic = cs*32 + k + 1)
//   [576,1008) : L1   [hidg2][cs3][tap9][g4][pl2]   (w1 ic = cs*32 + k)
// wxf (fp32):  [tap9][g4][mblock16][4]  -> w0 ic = 0 (the x channel), m=oc row
__global__ void wprep(const float* __restrict__ w0, const float* __restrict__ w1,
                      u16* __restrict__ wf, float* __restrict__ wxf)
{
    const int gid = blockIdx.x * 256 + threadIdx.x;
    if (gid < 1008 * 64) {
        const int lane = gid & 63;
        const int f = gid >> 6;
        const int m = lane & 15;
        const int kh = lane >> 4;
        float v[8];
        int pl;
        if (f < 576) {
            pl = f & 1;
            const int g = (f >> 1) & 3;
            int r = f >> 3;
            const int tap = r % 9; r /= 9;
            const int cs = r & 1;
            const int hidg = r >> 1;
            const int oc = g * 64 + hidg * 16 + m;
            #pragma unroll
            for (int j = 0; j < 8; ++j) {
                const int ic = cs * 32 + kh * 8 + j + 1;
                v[j] = w0[((size_t)oc * 65 + ic) * 9 + tap];
            }
        } else {
            const int f2 = f - 576;
            pl = f2 & 1;
            const int g = (f2 >> 1) & 3;
            int r = f2 >> 3;
            const int tap = r % 9; r /= 9;
            const int cs = r % 3;
            const int hidg = r / 3;
            const int oc = g * 32 + hidg * 16 + m;
            #pragma unroll
            for (int j = 0; j < 8; ++j) {
                const int ic = cs * 32 + kh * 8 + j;
                v[j] = w1[((size_t)oc * 96 + ic) * 9 + tap];
            }
        }
        u16 o[8] __attribute__((aligned(16)));
        #pragma unroll
        for (int j = 0; j < 8; ++j) {
            const u16 hi = f2bf(v[j]);
            o[j] = pl ? (u16)f2bf(v[j] - bf2f(hi)) : hi;
        }
        *(uint4*)(wf + (size_t)gid * 8) = *(const uint4*)o;
    }
    const int wx = gid - 1008 * 64;
    if (wx >= 0 && wx < 2304) {
        const int e = wx & 3;
        const int f4 = wx >> 2;
        const int mb = f4 & 15;
        const int tg = f4 >> 4;
        const int g = tg & 3;
        const int tap = tg >> 2;
        const int m = mb * 4 + e;
        wxf[wx] = w0[((size_t)(g * 64 + m) * 65 + 0) * 9 + tap];
    }
}

// x padded fp32 plane: [t][b][PADPX], zero guard (buffer memset beforehand).
__global__ void xprep(const float* __restrict__ x, float* __restrict__ xpad)
{
    const int gid = blockIdx.x * 256 + threadIdx.x;
    if (gid >= TT * BB * HWSZ) return;
    const int pix = gid % HWSZ;
    const int b = (gid / HWSZ) % BB;
    const int t = gid / (HWSZ * BB);
    const float v = x[((size_t)b * TT + t) * HWSZ + pix];
    const int y = pix / 48, xx = pix - y * 48;
    const int p = (y + 1) * 50 + (xx + 1);
    xpad[(size_t)(t * BB + b) * PADPX + POFF + p] = v;
}

// Merged-slot conv: per tap, issue ALL slot-pairs' B loads first, then the
// MFMA cluster with A loads interleaved -> 3x outstanding loads vs serial.
template<int NSL>
__device__ __forceinline__ void conv_block(
    f32x4 acc[2][4],
    const u16* __restrict__ in_hi, const u16* __restrict__ in_lo,
    size_t base0, size_t bstride, const char* pa0, size_t astride)
{
    const u16* pbh[NSL];
    const u16* pbl[NSL];
    const char* pa[NSL];
    #pragma unroll
    for (int sp = 0; sp < NSL; ++sp) {
        pbh[sp] = in_hi + base0 + (size_t)sp * bstride;
        pbl[sp] = in_lo + base0 + (size_t)sp * bstride;
        pa[sp]  = pa0 + (size_t)sp * astride;
    }
    #pragma unroll
    for (int tap = 0; tap < 9; ++tap) {
        const int toff = ((tap / 3) - 1) * 50 + (tap % 3) - 1;
        bf16x8 Bh0[NSL], Bl0[NSL], Bh1[NSL], Bl1[NSL];
        #pragma unroll
        for (int sp = 0; sp < NSL; ++sp) {
            Bh0[sp] = *(const bf16x8*)(pbh[sp] + (long)toff * 16);
            Bl0[sp] = *(const bf16x8*)(pbl[sp] + (long)toff * 16);
            Bh1[sp] = *(const bf16x8*)(pbh[sp] + (long)(toff + 16) * 16);
            Bl1[sp] = *(const bf16x8*)(pbl[sp] + (long)(toff + 16) * 16);
        }
        #pragma unroll
        for (int sp = 0; sp < NSL; ++sp) {
            #pragma unroll
            for (int g = 0; g < 4; ++g) {
                const bf16x8 Ah = *(const bf16x8*)(pa[sp] + (size_t)(tap * 8 + g * 2 + 0) * 1024);
                const bf16x8 Al = *(const bf16x8*)(pa[sp] + (size_t)(tap * 8 + g * 2 + 1) * 1024);
                acc[0][g] = __builtin_amdgcn_mfma_f32_16x16x32_bf16(Al, Bh0[sp], acc[0][g], 0, 0, 0);
                acc[1][g] = __builtin_amdgcn_mfma_f32_16x16x32_bf16(Al, Bh1[sp], acc[1][g], 0, 0, 0);
                acc[0][g] = __builtin_amdgcn_mfma_f32_16x16x32_bf16(Ah, Bl0[sp], acc[0][g], 0, 0, 0);
                acc[1][g] = __builtin_amdgcn_mfma_f32_16x16x32_bf16(Ah, Bl1[sp], acc[1][g], 0, 0, 0);
                acc[0][g] = __builtin_amdgcn_mfma_f32_16x16x32_bf16(Ah, Bh0[sp], acc[0][g], 0, 0, 0);
                acc[1][g] = __builtin_amdgcn_mfma_f32_16x16x32_bf16(Ah, Bh1[sp], acc[1][g], 0, 0, 0);
            }
        }
    }
}

// One step: L0(t) [units 0..3] and L1(t-1) [units 4..5]; no LDS, no barriers.
// Wave = 32 px (2 B-tiles of 16) x 16 hid x 4 gates, 16x16x32 split-bf16.
// 1-D grid, b = blockIdx.x & 7 -> batch pinned to one XCD.
// in/out buffers: [kslot6][b][PADPX][16ch] hi/lo (kslot 0-3 = h0, 4-5 = h1).
__global__ __launch_bounds__(512, 4) void mstep(
    const u16* __restrict__ in_hi, const u16* __restrict__ in_lo,
    u16* __restrict__ out_hi, u16* __restrict__ out_lo,
    const float* __restrict__ xpad,
    const u16* __restrict__ wf, const float* __restrict__ wxf,
    const float* __restrict__ b0, const float* __restrict__ b1,
    float* __restrict__ cbuf, float* __restrict__ seq_t,
    int t, int doL0, int doL1)
{
    const int tid = threadIdx.x;
    const int lane = tid & 63;
    const int wv = tid >> 6;
    const int lid = blockIdx.x;
    const int b = lid & 7;           // XCD selector
    const int r = lid >> 3;
    const int unit = r % 6;
    const int pg = r / 6;
    const bool isL0 = unit < 4;
    if (isL0) { if (!doL0) return; } else { if (!doL1) return; }
    const int frag = pg * 8 + wv;
    if (frag >= NWAVE) return;
    const int p0 = frag * 32;
    const int hidg = isL0 ? unit : (unit - 4);

    const int n   = lane & 15;        // px col within tile; also A row m
    const int khb = (lane >> 4) & 1;  // within-slot 8-ch half for B
    const int ksl = lane >> 5;        // slot parity for B
    const int mq  = lane >> 4;        // D row quarter: m = mq*4 + e

    // acc init = bias (D: col=lane&15, row m=mq*4+e)
    const float* bias = isL0 ? b0 : b1;
    const int CHID = isL0 ? 64 : 32;
    f32x4 acc[2][4];
    #pragma unroll
    for (int g = 0; g < 4; ++g) {
        const f32x4 bv = *(const f32x4*)(bias + g * CHID + hidg * 16 + mq * 4);
        acc[0][g] = bv;
        acc[1][g] = bv;
    }

    const size_t base0 = ((size_t)(ksl * 8 + b) * PADPX + POFF + p0 + n) * 16 + khb * 8;
    const size_t bstride = (size_t)2 * 8 * PADPX * 16;   // per slot-pair
    const size_t astride = (size_t)72 * 512 * 2;         // 73728 bytes per slot

    if (isL0) {
        const char* pa0 = (const char*)(wf + (size_t)((hidg * 2) * 72) * 512) + lane * 16;
        conv_block<2>(acc, in_hi, in_lo, base0, bstride, pa0, astride);
        // ---- x channel on VALU, exact fp32 ----
        const float* xrow = xpad + (size_t)(t * BB + b) * PADPX + POFF + p0 + n;
        #pragma unroll
        for (int tap = 0; tap < 9; ++tap) {
            const int toff = ((tap / 3) - 1) * 50 + (tap % 3) - 1;
            const float xv0 = xrow[toff];
            const float xv1 = xrow[toff + 16];
            #pragma unroll
            for (int g = 0; g < 4; ++g) {
                const f32x4 wvx = *(const f32x4*)(wxf +
                    ((size_t)(tap * 4 + g) * 16 + hidg * 4 + mq) * 4);
                #pragma unroll
                for (int e = 0; e < 4; ++e) {
                    acc[0][g][e] += wvx[e] * xv0;
                    acc[1][g][e] += wvx[e] * xv1;
                }
            }
        }
    } else {
        const char* pa0 = (const char*)(wf + (size_t)(576 + hidg * 3 * 72) * 512) + lane * 16;
        conv_block<3>(acc, in_hi, in_lo, base0, bstride, pa0, astride);
    }

    // ---- epilogue: LSTM pointwise; lane owns 2 px (one per tile), 4 m-rows ----
    // All stores below are write-once / read-next-launch -> non-temporal.
    const int slot = (unit * 8 + b) * NWAVE + frag;
    float* cs_ = cbuf + (size_t)slot * 512;
    #pragma unroll
    for (int tl = 0; tl < 2; ++tl) {
        const int p = p0 + tl * 16 + n;
        const int py = p / 50, pxx = p - py * 50;
        const bool valid = (py >= 1) && (py <= 48) && (pxx >= 1) && (pxx <= 48);
        const int pix = (py - 1) * 48 + (pxx - 1);
        const bool doseq = (!isL0) && (b == 0) && valid;
        float* cptr = cs_ + tl * 256 + lane * 4;
        f32x4 cp = __builtin_nontemporal_load((const f32x4*)cptr);
        f32x4 cn;
        s16x4 sh, sl;
        #pragma unroll
        for (int e = 0; e < 4; ++e) {
            const float i_ = sigm(acc[tl][0][e]);
            const float f_ = sigm(acc[tl][1][e]);
            const float o_ = sigm(acc[tl][2][e]);
            const float g_ = tanhf(acc[tl][3][e]);
            const float cv = f_ * cp[e] + i_ * g_;
            const float hv = o_ * tanhf(cv);
            cn[e] = cv;
            const u16 hi = f2bf(hv);
            sh[e] = (short)hi;
            sl[e] = (short)f2bf(hv - bf2f(hi));
            if (doseq) {
                const int ch = hidg * 16 + mq * 4 + e;
                __builtin_nontemporal_store(hv, seq_t + (size_t)ch * HWSZ + pix);
            }
        }
        __builtin_nontemporal_store(cn, (f32x4*)cptr);
        if (valid) {
            const int kslot = (isL0 ? 0 : 4) + hidg;
            const size_t ob = (((size_t)kslot * 8 + b) * PADPX + POFF + p) * 16 + mq * 4;
            __builtin_nontemporal_store(sh, (s16x4*)(out_hi + ob));
            __builtin_nontemporal_store(sl, (s16x4*)(out_lo + ob));
        }
    }
}

// out[k] = bl + sum_j wl[j] * seq_flat[32k+j]   (seq layout [t][32ch][2304px])
__global__ void head_kernel(const float* __restrict__ seq,
                            const float* __restrict__ wl,
                            const float* __restrict__ bl,
                            float* __restrict__ out, int nk)
{
    __shared__ float wls[32];
    if (threadIdx.x < 32) wls[threadIdx.x] = wl[threadIdx.x];
    __syncthreads();
    int k = blockIdx.x * 256 + threadIdx.x;
    if (k >= nk) return;
    const float4* p = (const float4*)(seq + (size_t)k * 32);
    float s = bl[0];
    #pragma unroll
    for (int q = 0; q < 8; ++q) {
        float4 f = p[q];
        s += f.x * wls[q * 4 + 0] + f.y * wls[q * 4 + 1]
           + f.z * wls[q * 4 + 2] + f.w * wls[q * 4 + 3];
    }
    out[k] = s;
}

extern "C" void kernel_launch(void* const* d_in, const int* in_sizes, int n_in,
                              void* d_out, int out_size, void* d_ws, size_t ws_size,
                              hipStream_t stream)
{
    const float* x  = (const float*)d_in[0];   // [8,32,1,48,48]
    const float* w0 = (const float*)d_in[1];   // [256,65,3,3]
    const float* b0 = (const float*)d_in[2];   // [256]
    const float* w1 = (const float*)d_in[3];   // [128,96,3,3]
    const float* b1 = (const float*)d_in[4];   // [128]
    const float* wl = (const float*)d_in[5];   // [1,32]
    const float* bl = (const float*)d_in[6];   // [1]
    float* out = (float*)d_out;                // [73728]

    char* p = (char*)d_ws;
    auto alloc = [&](size_t bytes) -> char* {
        char* r = p; p += (bytes + 255) & ~(size_t)255; return r;
    };
    const size_t inbytes = (size_t)6 * BB * PADPX * 16 * 2;   // 3.94 MB
    u16* inA_hi = (u16*)alloc(inbytes);
    u16* inA_lo = (u16*)alloc(inbytes);
    u16* inB_hi = (u16*)alloc(inbytes);
    u16* inB_lo = (u16*)alloc(inbytes);
    const size_t xbytes = (size_t)TT * BB * PADPX * 4;        // 2.75 MB
    float* xpad = (float*)alloc(xbytes);
    u16* wfall  = (u16*)alloc((size_t)1008 * 1024);           // 1.03 MB
    float* wxf  = (float*)alloc((size_t)2304 * 4);
    const size_t cbytes = (size_t)6 * BB * NWAVE * 512 * 4;   // 7.57 MB
    float* cbuf = (float*)alloc(cbytes);
    float* seq  = (float*)alloc((size_t)TT * 32 * HWSZ * 4);  // 9.44 MB

    hipMemsetAsync(inA_hi, 0, inbytes, stream);
    hipMemsetAsync(inA_lo, 0, inbytes, stream);
    hipMemsetAsync(inB_hi, 0, inbytes, stream);
    hipMemsetAsync(inB_lo, 0, inbytes, stream);
    hipMemsetAsync(xpad, 0, xbytes, stream);
    hipMemsetAsync(cbuf, 0, cbytes, stream);

    wprep<<<(1008 * 64 + 2304 + 255) / 256, 256, 0, stream>>>(w0, w1, wfall, wxf);
    xprep<<<(TT * BB * HWSZ + 255) / 256, 256, 0, stream>>>(x, xpad);

    for (int s = 0; s <= TT; ++s) {
        const u16* cih = (s & 1) ? inB_hi : inA_hi;
        const u16* cil = (s & 1) ? inB_lo : inA_lo;
        u16* noh = (s & 1) ? inA_hi : inB_hi;
        u16* nol = (s & 1) ? inA_lo : inB_lo;
        const int tq = (s >= 1) ? (s - 1) : 0;
        mstep<<<dim3(480), 512, 0, stream>>>(
            cih, cil, noh, nol, xpad, wfall, wxf, b0, b1,
            cbuf, seq + (size_t)tq * 32 * HWSZ,
            (s < TT) ? s : 0, (s < TT) ? 1 : 0, (s >= 1) ? 1 : 0);
    }
    head_kernel<<<288, 256, 0, stream>>>(seq, wl, bl, out, 73728);
}